// Round 11
// baseline (506.008 us; speedup 1.0000x reference)
//
#include <hip/hip_runtime.h>

#define B_    32
#define CIN_  64
#define COUT_ 64
#define IMG_  128
#define W4_   32                 // float4 per row
#define PIX4_ 4096               // float4 per plane
#define NPOS_ (B_ * PIX4_)       // 131072 float4 positions
#define REPA_ 16                 // DIAGNOSTIC repeats (idempotent)
#define REPB_ 8

// ---- Kernel A (diag x16): R7's ch_sum2 body, unchanged, in a rep loop. ----
__global__ __launch_bounds__(256) void ch_sum2_rep(const float* __restrict__ x,
                                                   float* __restrict__ part) {
    const int g   = blockIdx.y;                    // 0..1 channel group
    const int tid = threadIdx.x;
    const int i0  = blockIdx.x * 512 + tid;        // chunk of 512 float4
    const int i1  = i0 + 256;
    const int b   = i0 >> 12;
    const int p0  = i0 & (PIX4_ - 1);

    const float4* xp = reinterpret_cast<const float4*>(x)
                     + ((size_t)b * CIN_ + (size_t)g * 32) * PIX4_ + p0;
    float4* pp = reinterpret_cast<float4*>(part) + (size_t)g * NPOS_;

    for (int rep = 0; rep < REPA_; ++rep) {
        float4 a0 = make_float4(0.f, 0.f, 0.f, 0.f);
        float4 a1 = make_float4(0.f, 0.f, 0.f, 0.f);
#pragma unroll 8
        for (int c = 0; c < 32; ++c) {
            float4 v0 = xp[(size_t)c * PIX4_];
            float4 v1 = xp[(size_t)c * PIX4_ + 256];
            a0.x += v0.x; a0.y += v0.y; a0.z += v0.z; a0.w += v0.w;
            a1.x += v1.x; a1.y += v1.y; a1.z += v1.z; a1.w += v1.w;
        }
        pp[i0] = a0;
        pp[i1] = a1;
        asm volatile("" ::: "memory");             // no hoist/elide across reps
    }
}

// ---- Kernel B (diag x8): R7's conv_shfl body, unchanged, in a rep loop. ----
__global__ __launch_bounds__(256) void conv_shfl_rep(const float* __restrict__ part,
                                                     const float* __restrict__ kern,
                                                     const float* __restrict__ bias,
                                                     float* __restrict__ out) {
    const int n   = blockIdx.x;                    // 0..4095
    const int swz = (n & 7) * 512 + (n >> 3);      // bijective XCD chunking
    const int co   = swz & 63;
    const int half = (swz >> 6) & 1;
    const int b    = swz >> 7;
    const int tid  = threadIdx.x;
    const int w4   = tid & 31;
    const int rb   = (tid >> 5) * 8;               // local output rows rb..rb+7
    const int r0   = half * 64;

    const float4* p0 = reinterpret_cast<const float4*>(part) + (size_t)b * PIX4_;
    const float4* p1 = p0 + (size_t)NPOS_;

    const float* kw = kern + co * 9;
    const float k0 = kw[0], k1 = kw[1], k2 = kw[2];
    const float k3 = kw[3], k4 = kw[4], k5 = kw[5];
    const float k6 = kw[6], k7 = kw[7], k8 = kw[8];
    const float bv = (float)CIN_ * bias[co];

    float4* outp = reinterpret_cast<float4*>(out) + (size_t)(b * COUT_ + co) * PIX4_;

    for (int rep = 0; rep < REPB_; ++rep) {
        float4 C[10];
#pragma unroll
        for (int r = 0; r < 10; ++r) {
            const int row = r0 + rb - 1 + r;
            float4 v = make_float4(0.f, 0.f, 0.f, 0.f);
            if (row >= 0 && row < IMG_) {
                float4 u0 = p0[row * W4_ + w4];
                float4 u1 = p1[row * W4_ + w4];
                v = make_float4(u0.x + u1.x, u0.y + u1.y, u0.z + u1.z, u0.w + u1.w);
            }
            C[r] = v;
        }

        float Lw[10], Rx[10];
#pragma unroll
        for (int r = 0; r < 10; ++r) {
            float lw = __shfl_up(C[r].w, 1, 32);
            float rx = __shfl_down(C[r].x, 1, 32);
            Lw[r] = (w4 > 0)  ? lw : 0.f;
            Rx[r] = (w4 < 31) ? rx : 0.f;
        }

#pragma unroll
        for (int j = 0; j < 8; ++j) {
            float4 a;
            a.x = bv + k0 * Lw[j]     + k1 * C[j].x     + k2 * C[j].y
                     + k3 * Lw[j + 1] + k4 * C[j + 1].x + k5 * C[j + 1].y
                     + k6 * Lw[j + 2] + k7 * C[j + 2].x + k8 * C[j + 2].y;
            a.y = bv + k0 * C[j].x     + k1 * C[j].y     + k2 * C[j].z
                     + k3 * C[j + 1].x + k4 * C[j + 1].y + k5 * C[j + 1].z
                     + k6 * C[j + 2].x + k7 * C[j + 2].y + k8 * C[j + 2].z;
            a.z = bv + k0 * C[j].y     + k1 * C[j].z     + k2 * C[j].w
                     + k3 * C[j + 1].y + k4 * C[j + 1].z + k5 * C[j + 1].w
                     + k6 * C[j + 2].y + k7 * C[j + 2].z + k8 * C[j + 2].w;
            a.w = bv + k0 * C[j].z     + k1 * C[j].w     + k2 * Rx[j]
                     + k3 * C[j + 1].z + k4 * C[j + 1].w + k5 * Rx[j + 1]
                     + k6 * C[j + 2].z + k7 * C[j + 2].w + k8 * Rx[j + 2];
            outp[(size_t)(r0 + rb + j) * W4_ + w4] = a;
        }
        asm volatile("" ::: "memory");
    }
}

extern "C" void kernel_launch(void* const* d_in, const int* in_sizes, int n_in,
                              void* d_out, int out_size, void* d_ws, size_t ws_size,
                              hipStream_t stream) {
    const float* x    = (const float*)d_in[0];   // (32,64,128,128) f32
    const float* kern = (const float*)d_in[1];   // (64,3,3) f32
    const float* bias = (const float*)d_in[2];   // (64,1,1,1) f32
    float* out  = (float*)d_out;                 // (32,64,128,128) f32
    float* part = (float*)d_ws;                  // 2 x 2 MiB partial planes

    dim3 ga(NPOS_ / 512, 2);                     // (256, 2) = 512 blocks
    ch_sum2_rep<<<ga, 256, 0, stream>>>(x, part);

    conv_shfl_rep<<<dim3(B_ * COUT_ * 2), 256, 0, stream>>>(part, kern, bias, out);
}

// Round 13
// 66.979 us; speedup vs baseline: 7.5548x; 7.5548x over previous
//
#include <hip/hip_runtime.h>

#define B_    32
#define CIN_  64
#define COUT_ 64
#define IMG_  128
#define W4_   32                 // float4 per row
#define PIX4_ 4096               // float4 per plane
#define NPOS_ (B_ * PIX4_)       // 131072 float4 positions

// Role-split stage kernel, NO inter-block sync. Blocks [0,na): A-units
// (channel-sum of 512-float4 chunk) for batches [ab, ab+na/16). Blocks
// [na, na+nb): B-units (conv_shfl) for batches [bb, bb+nb/128) — these read
// partials produced by a PREVIOUS dispatch, so no ordering is needed here.
__global__ __launch_bounds__(256) void gc_stage(
    const float* __restrict__ x, const float* __restrict__ kern,
    const float* __restrict__ bias, float* __restrict__ out,
    float* __restrict__ part, int na, int ab, int bb)
{
    const int n = blockIdx.x, tid = threadIdx.x;

    if (n < na) {
        // ---- A-unit: 16 units per batch: (g, q) = (unit>>3, unit&7) ----
        const int b = ab + (n >> 4), sub = n & 15, g = sub >> 3, q = sub & 7;
        const int p0 = q * 512 + tid, p1 = p0 + 256;
        const float4* xp = reinterpret_cast<const float4*>(x)
                         + ((size_t)b * CIN_ + (size_t)g * 32) * PIX4_;
        float4 a0 = make_float4(0.f, 0.f, 0.f, 0.f);
        float4 a1 = make_float4(0.f, 0.f, 0.f, 0.f);
#pragma unroll 8
        for (int c = 0; c < 32; ++c) {
            float4 v0 = xp[(size_t)c * PIX4_ + p0];
            float4 v1 = xp[(size_t)c * PIX4_ + p1];
            a0.x += v0.x; a0.y += v0.y; a0.z += v0.z; a0.w += v0.w;
            a1.x += v1.x; a1.y += v1.y; a1.z += v1.z; a1.w += v1.w;
        }
        float4* pp = reinterpret_cast<float4*>(part)
                   + (size_t)g * NPOS_ + (size_t)b * PIX4_;
        pp[p0] = a0;
        pp[p1] = a1;
        return;
    }

    // ---- B-unit: m in [0, 2048) -> (b, co, half) via XCD-chunked swizzle ----
    const int m   = n - na;
    const int swz = (m & 7) * 256 + (m >> 3);      // bijective on [0,2048)
    const int co   = swz & 63;
    const int half = (swz >> 6) & 1;
    const int b    = bb + (swz >> 7);              // 16 batches per stage
    const int w4   = tid & 31;
    const int rb   = (tid >> 5) * 8;               // local output rows rb..rb+7
    const int r0   = half * 64;

    const float4* p0p = reinterpret_cast<const float4*>(part) + (size_t)b * PIX4_;
    const float4* p1p = p0p + (size_t)NPOS_;

    float4 C[10];
#pragma unroll
    for (int r = 0; r < 10; ++r) {
        const int row = r0 + rb - 1 + r;
        float4 v = make_float4(0.f, 0.f, 0.f, 0.f);
        if (row >= 0 && row < IMG_) {
            float4 u0 = p0p[row * W4_ + w4];
            float4 u1 = p1p[row * W4_ + w4];
            v = make_float4(u0.x + u1.x, u0.y + u1.y, u0.z + u1.z, u0.w + u1.w);
        }
        C[r] = v;
    }

    float Lw[10], Rx[10];
#pragma unroll
    for (int r = 0; r < 10; ++r) {
        float lw = __shfl_up(C[r].w, 1, 32);
        float rx = __shfl_down(C[r].x, 1, 32);
        Lw[r] = (w4 > 0)  ? lw : 0.f;
        Rx[r] = (w4 < 31) ? rx : 0.f;
    }

    const float* kw = kern + co * 9;
    const float k0 = kw[0], k1 = kw[1], k2 = kw[2];
    const float k3 = kw[3], k4 = kw[4], k5 = kw[5];
    const float k6 = kw[6], k7 = kw[7], k8 = kw[8];
    const float bv = (float)CIN_ * bias[co];

    float4* outp = reinterpret_cast<float4*>(out) + (size_t)(b * COUT_ + co) * PIX4_;

#pragma unroll
    for (int j = 0; j < 8; ++j) {                  // rows j, j+1, j+2 of C
        float4 a;
        a.x = bv + k0 * Lw[j]     + k1 * C[j].x     + k2 * C[j].y
                 + k3 * Lw[j + 1] + k4 * C[j + 1].x + k5 * C[j + 1].y
                 + k6 * Lw[j + 2] + k7 * C[j + 2].x + k8 * C[j + 2].y;
        a.y = bv + k0 * C[j].x     + k1 * C[j].y     + k2 * C[j].z
                 + k3 * C[j + 1].x + k4 * C[j + 1].y + k5 * C[j + 1].z
                 + k6 * C[j + 2].x + k7 * C[j + 2].y + k8 * C[j + 2].z;
        a.z = bv + k0 * C[j].y     + k1 * C[j].z     + k2 * C[j].w
                 + k3 * C[j + 1].y + k4 * C[j + 1].z + k5 * C[j + 1].w
                 + k6 * C[j + 2].y + k7 * C[j + 2].z + k8 * C[j + 2].w;
        a.w = bv + k0 * C[j].z     + k1 * C[j].w     + k2 * Rx[j]
                 + k3 * C[j + 1].z + k4 * C[j + 1].w + k5 * Rx[j + 1]
                 + k6 * C[j + 2].z + k7 * C[j + 2].w + k8 * Rx[j + 2];
        outp[(size_t)(r0 + rb + j) * W4_ + w4] = a;
    }
}

extern "C" void kernel_launch(void* const* d_in, const int* in_sizes, int n_in,
                              void* d_out, int out_size, void* d_ws, size_t ws_size,
                              hipStream_t stream) {
    const float* x    = (const float*)d_in[0];   // (32,64,128,128) f32
    const float* kern = (const float*)d_in[1];   // (64,3,3) f32
    const float* bias = (const float*)d_in[2];   // (64,1,1,1) f32
    float* out  = (float*)d_out;                 // (32,64,128,128) f32
    float* part = (float*)d_ws;                  // 2 x 2 MiB partial planes

    // S1: A for b[0,16)
    gc_stage<<<dim3(256), 256, 0, stream>>>(x, kern, bias, out, part,
                                            256, 0, 0);
    // S2: A for b[16,32) overlapped with B for b[0,16)
    gc_stage<<<dim3(256 + 2048), 256, 0, stream>>>(x, kern, bias, out, part,
                                                   256, 16, 0);
    // S3: B for b[16,32)
    gc_stage<<<dim3(2048), 256, 0, stream>>>(x, kern, bias, out, part,
                                             0, 0, 16);
}

// Round 14
// 61.832 us; speedup vs baseline: 8.1836x; 1.0832x over previous
//
#include <hip/hip_runtime.h>

#define B_    32
#define CIN_  64
#define COUT_ 64
#define IMG_  128
#define W4_   32                 // float4 per row
#define PIX4_ 4096               // float4 per plane
#define NPOS_ (B_ * PIX4_)       // 131072 float4 positions

typedef float f4v __attribute__((ext_vector_type(4)));

// ---- Kernel A: 2-group partial channel sums (512 blocks), R7 structure,
// with NONTEMPORAL x loads (bypass L3 allocation -> out/part stay resident
// across graph replays). Reads 134 MB, writes 8 MB of partials. ----
__global__ __launch_bounds__(256) void ch_sum2(const float* __restrict__ x,
                                               float* __restrict__ part) {
    const int g   = blockIdx.y;                    // 0..1 channel group
    const int tid = threadIdx.x;
    const int i0  = blockIdx.x * 512 + tid;        // chunk of 512 float4
    const int i1  = i0 + 256;
    const int b   = i0 >> 12;
    const int p0  = i0 & (PIX4_ - 1);

    const f4v* xp = reinterpret_cast<const f4v*>(x)
                  + ((size_t)b * CIN_ + (size_t)g * 32) * PIX4_ + p0;

    f4v a0 = {0.f, 0.f, 0.f, 0.f};
    f4v a1 = {0.f, 0.f, 0.f, 0.f};
#pragma unroll 8
    for (int c = 0; c < 32; ++c) {
        f4v v0 = __builtin_nontemporal_load(xp + (size_t)c * PIX4_);
        f4v v1 = __builtin_nontemporal_load(xp + (size_t)c * PIX4_ + 256);
        a0 += v0;
        a1 += v1;
    }
    f4v* pp = reinterpret_cast<f4v*>(part) + (size_t)g * NPOS_;
    pp[i0] = a0;
    pp[i1] = a1;
}

// ---- Kernel B: R7's conv_shfl, unchanged. Block = (b, co, half-plane);
// thread owns 8 rows at fixed w4; halo via shfl; sequential stores. ----
__global__ __launch_bounds__(256) void conv_shfl(const float* __restrict__ part,
                                                 const float* __restrict__ kern,
                                                 const float* __restrict__ bias,
                                                 float* __restrict__ out) {
    const int n   = blockIdx.x;                    // 0..4095
    const int swz = (n & 7) * 512 + (n >> 3);      // bijective XCD chunking
    const int co   = swz & 63;
    const int half = (swz >> 6) & 1;
    const int b    = swz >> 7;
    const int tid  = threadIdx.x;
    const int w4   = tid & 31;
    const int rb   = (tid >> 5) * 8;               // local output rows rb..rb+7
    const int r0   = half * 64;

    const float4* p0 = reinterpret_cast<const float4*>(part) + (size_t)b * PIX4_;
    const float4* p1 = p0 + (size_t)NPOS_;

    float4 C[10];
#pragma unroll
    for (int r = 0; r < 10; ++r) {
        const int row = r0 + rb - 1 + r;
        float4 v = make_float4(0.f, 0.f, 0.f, 0.f);
        if (row >= 0 && row < IMG_) {
            float4 u0 = p0[row * W4_ + w4];
            float4 u1 = p1[row * W4_ + w4];
            v = make_float4(u0.x + u1.x, u0.y + u1.y, u0.z + u1.z, u0.w + u1.w);
        }
        C[r] = v;
    }

    float Lw[10], Rx[10];
#pragma unroll
    for (int r = 0; r < 10; ++r) {
        float lw = __shfl_up(C[r].w, 1, 32);
        float rx = __shfl_down(C[r].x, 1, 32);
        Lw[r] = (w4 > 0)  ? lw : 0.f;
        Rx[r] = (w4 < 31) ? rx : 0.f;
    }

    const float* kw = kern + co * 9;
    const float k0 = kw[0], k1 = kw[1], k2 = kw[2];
    const float k3 = kw[3], k4 = kw[4], k5 = kw[5];
    const float k6 = kw[6], k7 = kw[7], k8 = kw[8];
    const float bv = (float)CIN_ * bias[co];

    float4* outp = reinterpret_cast<float4*>(out) + (size_t)(b * COUT_ + co) * PIX4_;

#pragma unroll
    for (int j = 0; j < 8; ++j) {                  // rows j, j+1, j+2 of C
        float4 a;
        a.x = bv + k0 * Lw[j]     + k1 * C[j].x     + k2 * C[j].y
                 + k3 * Lw[j + 1] + k4 * C[j + 1].x + k5 * C[j + 1].y
                 + k6 * Lw[j + 2] + k7 * C[j + 2].x + k8 * C[j + 2].y;
        a.y = bv + k0 * C[j].x     + k1 * C[j].y     + k2 * C[j].z
                 + k3 * C[j + 1].x + k4 * C[j + 1].y + k5 * C[j + 1].z
                 + k6 * C[j + 2].x + k7 * C[j + 2].y + k8 * C[j + 2].z;
        a.z = bv + k0 * C[j].y     + k1 * C[j].z     + k2 * C[j].w
                 + k3 * C[j + 1].y + k4 * C[j + 1].z + k5 * C[j + 1].w
                 + k6 * C[j + 2].y + k7 * C[j + 2].z + k8 * C[j + 2].w;
        a.w = bv + k0 * C[j].z     + k1 * C[j].w     + k2 * Rx[j]
                 + k3 * C[j + 1].z + k4 * C[j + 1].w + k5 * Rx[j + 1]
                 + k6 * C[j + 2].z + k7 * C[j + 2].w + k8 * Rx[j + 2];
        outp[(size_t)(r0 + rb + j) * W4_ + w4] = a;
    }
}

extern "C" void kernel_launch(void* const* d_in, const int* in_sizes, int n_in,
                              void* d_out, int out_size, void* d_ws, size_t ws_size,
                              hipStream_t stream) {
    const float* x    = (const float*)d_in[0];   // (32,64,128,128) f32
    const float* kern = (const float*)d_in[1];   // (64,3,3) f32
    const float* bias = (const float*)d_in[2];   // (64,1,1,1) f32
    float* out  = (float*)d_out;                 // (32,64,128,128) f32
    float* part = (float*)d_ws;                  // 2 x 2 MiB partial planes

    dim3 ga(NPOS_ / 512, 2);                     // (256, 2) = 512 blocks
    ch_sum2<<<ga, 256, 0, stream>>>(x, part);

    conv_shfl<<<dim3(B_ * COUT_ * 2), 256, 0, stream>>>(part, kern, bias, out);
}

// Round 15
// 60.368 us; speedup vs baseline: 8.3821x; 1.0243x over previous
//
#include <hip/hip_runtime.h>

#define B_    32
#define CIN_  64
#define COUT_ 64
#define IMG_  128
#define W4_   32                 // float4 per row
#define PIX4_ 4096               // float4 per plane
#define NPOS_ (B_ * PIX4_)       // 131072 float4 positions

// ---- Kernel A: 2-group partial channel sums (512 blocks). Reads 134 MB,
// writes 8 MB of partials. 8 KiB-contiguous per-channel chunks, unroll-8
// keeps 16 independent float4 loads in flight per thread. ----
__global__ __launch_bounds__(256) void ch_sum2(const float* __restrict__ x,
                                               float* __restrict__ part) {
    const int g   = blockIdx.y;                    // 0..1 channel group
    const int tid = threadIdx.x;
    const int i0  = blockIdx.x * 512 + tid;        // chunk of 512 float4
    const int i1  = i0 + 256;
    const int b   = i0 >> 12;
    const int p0  = i0 & (PIX4_ - 1);

    const float4* xp = reinterpret_cast<const float4*>(x)
                     + ((size_t)b * CIN_ + (size_t)g * 32) * PIX4_ + p0;

    float4 a0 = make_float4(0.f, 0.f, 0.f, 0.f);
    float4 a1 = make_float4(0.f, 0.f, 0.f, 0.f);
#pragma unroll 8
    for (int c = 0; c < 32; ++c) {
        float4 v0 = xp[(size_t)c * PIX4_];
        float4 v1 = xp[(size_t)c * PIX4_ + 256];
        a0.x += v0.x; a0.y += v0.y; a0.z += v0.z; a0.w += v0.w;
        a1.x += v1.x; a1.y += v1.y; a1.z += v1.z; a1.w += v1.w;
    }
    float4* pp = reinterpret_cast<float4*>(part) + (size_t)g * NPOS_;
    pp[i0] = a0;
    pp[i1] = a1;
}

// ---- Kernel B: no LDS. Block = (b, co, half-plane). Each thread owns 8
// consecutive rows at fixed w4: loads its 10-row float4 column from the two
// L2/L3-resident partial planes (20 coalesced b128 loads), halo scalars via
// shfl, streams 8 sequential float4 stores. Zero bank conflicts. ----
__global__ __launch_bounds__(256) void conv_shfl(const float* __restrict__ part,
                                                 const float* __restrict__ kern,
                                                 const float* __restrict__ bias,
                                                 float* __restrict__ out) {
    const int n   = blockIdx.x;                    // 0..4095
    const int swz = (n & 7) * 512 + (n >> 3);      // bijective XCD chunking
    const int co   = swz & 63;
    const int half = (swz >> 6) & 1;
    const int b    = swz >> 7;
    const int tid  = threadIdx.x;
    const int w4   = tid & 31;
    const int rb   = (tid >> 5) * 8;               // local output rows rb..rb+7
    const int r0   = half * 64;

    const float4* p0 = reinterpret_cast<const float4*>(part) + (size_t)b * PIX4_;
    const float4* p1 = p0 + (size_t)NPOS_;

    // 10-row column of summed partials (C), all loads issued up front.
    float4 C[10];
#pragma unroll
    for (int r = 0; r < 10; ++r) {
        const int row = r0 + rb - 1 + r;
        float4 v = make_float4(0.f, 0.f, 0.f, 0.f);
        if (row >= 0 && row < IMG_) {
            float4 u0 = p0[row * W4_ + w4];
            float4 u1 = p1[row * W4_ + w4];
            v = make_float4(u0.x + u1.x, u0.y + u1.y, u0.z + u1.z, u0.w + u1.w);
        }
        C[r] = v;
    }

    // Halo scalars from neighbors (32-lane segments = one w4 row group).
    float Lw[10], Rx[10];
#pragma unroll
    for (int r = 0; r < 10; ++r) {
        float lw = __shfl_up(C[r].w, 1, 32);
        float rx = __shfl_down(C[r].x, 1, 32);
        Lw[r] = (w4 > 0)  ? lw : 0.f;
        Rx[r] = (w4 < 31) ? rx : 0.f;
    }

    const float* kw = kern + co * 9;
    const float k0 = kw[0], k1 = kw[1], k2 = kw[2];
    const float k3 = kw[3], k4 = kw[4], k5 = kw[5];
    const float k6 = kw[6], k7 = kw[7], k8 = kw[8];
    const float bv = (float)CIN_ * bias[co];

    float4* outp = reinterpret_cast<float4*>(out) + (size_t)(b * COUT_ + co) * PIX4_;

#pragma unroll
    for (int j = 0; j < 8; ++j) {                  // rows j, j+1, j+2 of C
        float4 a;
        a.x = bv + k0 * Lw[j]     + k1 * C[j].x     + k2 * C[j].y
                 + k3 * Lw[j + 1] + k4 * C[j + 1].x + k5 * C[j + 1].y
                 + k6 * Lw[j + 2] + k7 * C[j + 2].x + k8 * C[j + 2].y;
        a.y = bv + k0 * C[j].x     + k1 * C[j].y     + k2 * C[j].z
                 + k3 * C[j + 1].x + k4 * C[j + 1].y + k5 * C[j + 1].z
                 + k6 * C[j + 2].x + k7 * C[j + 2].y + k8 * C[j + 2].z;
        a.z = bv + k0 * C[j].y     + k1 * C[j].z     + k2 * C[j].w
                 + k3 * C[j + 1].y + k4 * C[j + 1].z + k5 * C[j + 1].w
                 + k6 * C[j + 2].y + k7 * C[j + 2].z + k8 * C[j + 2].w;
        a.w = bv + k0 * C[j].z     + k1 * C[j].w     + k2 * Rx[j]
                 + k3 * C[j + 1].z + k4 * C[j + 1].w + k5 * Rx[j + 1]
                 + k6 * C[j + 2].z + k7 * C[j + 2].w + k8 * Rx[j + 2];
        outp[(size_t)(r0 + rb + j) * W4_ + w4] = a;
    }
}

extern "C" void kernel_launch(void* const* d_in, const int* in_sizes, int n_in,
                              void* d_out, int out_size, void* d_ws, size_t ws_size,
                              hipStream_t stream) {
    const float* x    = (const float*)d_in[0];   // (32,64,128,128) f32
    const float* kern = (const float*)d_in[1];   // (64,3,3) f32
    const float* bias = (const float*)d_in[2];   // (64,1,1,1) f32
    float* out  = (float*)d_out;                 // (32,64,128,128) f32
    float* part = (float*)d_ws;                  // 2 x 2 MiB partial planes

    dim3 ga(NPOS_ / 512, 2);                     // (256, 2) = 512 blocks
    ch_sum2<<<ga, 256, 0, stream>>>(x, part);

    conv_shfl<<<dim3(B_ * COUT_ * 2), 256, 0, stream>>>(part, kern, bias, out);
}